// Round 15
// baseline (91.189 us; speedup 1.0000x reference)
//
#include <hip/hip_runtime.h>
#include <hip/hip_bf16.h>

#define NT 256
#define R2f 0.70710678118654752f
#define CS1 0.92387953251128674f   // cos(pi/8)
#define SN1 0.38268343236508978f   // sin(pi/8)
#define PI2 6.2831853071795865f
#define LDSN 4336                  // 4096 + 16 pad per 256

__device__ __forceinline__ float2 cmulf(float2 a, float2 b) {
    return make_float2(a.x * b.x - a.y * b.y, a.x * b.y + a.y * b.x);
}
__device__ __forceinline__ float2 cadd(float2 a, float2 b) { return make_float2(a.x + b.x, a.y + b.y); }
__device__ __forceinline__ float2 csub(float2 a, float2 b) { return make_float2(a.x - b.x, a.y - b.y); }
__device__ __forceinline__ int padx(int i) { return i + ((i >> 8) << 4); }   // +16 per 256 segment

template<bool INV>
__device__ __forceinline__ float2 tww(float2 v, float wx, float wy) {
    float sy = INV ? -wy : wy;
    return make_float2(v.x * wx - v.y * sy, v.x * sy + v.y * wx);
}
template<bool INV>
__device__ __forceinline__ float2 mul_mi(float2 v) {
    return INV ? make_float2(-v.y, v.x) : make_float2(v.y, -v.x);
}

template<bool INV>
__device__ __forceinline__ void dft4(float2& a, float2& b, float2& c, float2& d) {
    float2 t0 = cadd(a, c), t1 = csub(a, c);
    float2 t2 = cadd(b, d), t3 = csub(b, d);
    float2 jt3 = mul_mi<INV>(t3);
    a = cadd(t0, t2);
    c = csub(t0, t2);
    b = cadd(t1, jt3);
    d = csub(t1, jt3);
}

template<bool INV>
__device__ __forceinline__ void fft16_tail(float2 v[16]) {
    v[5]  = tww<INV>(v[5],  CS1, -SN1);
    v[9]  = tww<INV>(v[9],  R2f, -R2f);
    v[13] = tww<INV>(v[13], SN1, -CS1);
    v[6]  = tww<INV>(v[6],  R2f, -R2f);
    v[10] = mul_mi<INV>(v[10]);
    v[14] = tww<INV>(v[14], -R2f, -R2f);
    v[7]  = tww<INV>(v[7],  SN1, -CS1);
    v[11] = tww<INV>(v[11], -R2f, -R2f);
    v[15] = tww<INV>(v[15], -CS1,  SN1);
    dft4<INV>(v[0],  v[1],  v[2],  v[3]);
    dft4<INV>(v[4],  v[5],  v[6],  v[7]);
    dft4<INV>(v[8],  v[9],  v[10], v[11]);
    dft4<INV>(v[12], v[13], v[14], v[15]);
    float2 t;
    t = v[1];  v[1]  = v[4];  v[4]  = t;
    t = v[2];  v[2]  = v[8];  v[8]  = t;
    t = v[3];  v[3]  = v[12]; v[12] = t;
    t = v[6];  v[6]  = v[9];  v[9]  = t;
    t = v[7];  v[7]  = v[13]; v[13] = t;
    t = v[11]; v[11] = v[14]; v[14] = t;
}

template<bool INV>
__device__ __forceinline__ void fft16(float2 v[16]) {
    dft4<INV>(v[0], v[4], v[8],  v[12]);
    dft4<INV>(v[1], v[5], v[9],  v[13]);
    dft4<INV>(v[2], v[6], v[10], v[14]);
    dft4<INV>(v[3], v[7], v[11], v[15]);
    fft16_tail<INV>(v);
}

// Forward 16-point DFT with v[8..15] known to be zero on entry.
__device__ __forceinline__ void fft16_hz(float2 v[16]) {
    #pragma unroll
    for (int i = 0; i < 4; ++i) {
        float2 a = v[i], b = v[i + 4];
        float2 jb = make_float2(b.y, -b.x);     // -i*b
        v[i]      = cadd(a, b);
        v[i + 4]  = cadd(a, jb);
        v[i + 8]  = csub(a, b);
        v[i + 12] = csub(a, jb);
    }
    fft16_tail<false>(v);
}

template<bool INV>
__device__ __forceinline__ void twchain(float2 v[16], float ang) {
    float s, c;
    __sincosf(INV ? ang : -ang, &s, &c);
    float2 w = make_float2(c, s);
    float2 t = w;
    v[1] = cmulf(v[1], t);
    #pragma unroll
    for (int a = 2; a < 16; ++a) { t = cmulf(t, w); v[a] = cmulf(v[a], t); }
}

// 4096-pt FFT, 256 threads, 16 regs/thread, float LDS region of LDSN entries.
// Component-split exchanges (x then y) halve LDS vs float2, bit-identical math.
template<bool INV>
__device__ void fft4096(float2 v[16], float* ldsf, int tid) {
    const int hi = tid >> 4, lo = tid & 15;
    if (!INV) {
        fft16_hz(v);
        twchain<false>(v, PI2 * (float)tid * (1.0f / 4096.0f));
        __syncthreads();
        #pragma unroll
        for (int a = 0; a < 16; ++a) ldsf[padx(tid + 256 * a)] = v[a].x;
        __syncthreads();
        #pragma unroll
        for (int m1 = 0; m1 < 16; ++m1) v[m1].x = ldsf[padx(m1 * 16 + lo + 256 * hi)];
        __syncthreads();
        #pragma unroll
        for (int a = 0; a < 16; ++a) ldsf[padx(tid + 256 * a)] = v[a].y;
        __syncthreads();
        #pragma unroll
        for (int m1 = 0; m1 < 16; ++m1) v[m1].y = ldsf[padx(m1 * 16 + lo + 256 * hi)];
        fft16<false>(v);
        twchain<false>(v, PI2 * (float)lo * (1.0f / 256.0f));
        __syncthreads();
        #pragma unroll
        for (int b = 0; b < 16; ++b) ldsf[padx((lo + 16 * b + 256 * hi) ^ b)] = v[b].x;
        __syncthreads();
        #pragma unroll
        for (int m0 = 0; m0 < 16; ++m0) v[m0].x = ldsf[padx((m0 + 16 * lo + 256 * hi) ^ lo)];
        __syncthreads();
        #pragma unroll
        for (int b = 0; b < 16; ++b) ldsf[padx((lo + 16 * b + 256 * hi) ^ b)] = v[b].y;
        __syncthreads();
        #pragma unroll
        for (int m0 = 0; m0 < 16; ++m0) v[m0].y = ldsf[padx((m0 + 16 * lo + 256 * hi) ^ lo)];
        fft16<false>(v);
    } else {
        fft16<true>(v);
        __syncthreads();
        #pragma unroll
        for (int m0 = 0; m0 < 16; ++m0) ldsf[padx((m0 + 16 * lo + 256 * hi) ^ lo)] = v[m0].x;
        __syncthreads();
        #pragma unroll
        for (int b = 0; b < 16; ++b) v[b].x = ldsf[padx((lo + 16 * b + 256 * hi) ^ b)];
        __syncthreads();
        #pragma unroll
        for (int m0 = 0; m0 < 16; ++m0) ldsf[padx((m0 + 16 * lo + 256 * hi) ^ lo)] = v[m0].y;
        __syncthreads();
        #pragma unroll
        for (int b = 0; b < 16; ++b) v[b].y = ldsf[padx((lo + 16 * b + 256 * hi) ^ b)];
        twchain<true>(v, PI2 * (float)lo * (1.0f / 256.0f));
        fft16<true>(v);
        __syncthreads();
        #pragma unroll
        for (int m1 = 0; m1 < 16; ++m1) ldsf[padx(m1 * 16 + lo + 256 * hi)] = v[m1].x;
        __syncthreads();
        #pragma unroll
        for (int a = 0; a < 16; ++a) v[a].x = ldsf[padx(tid + 256 * a)];
        __syncthreads();
        #pragma unroll
        for (int m1 = 0; m1 < 16; ++m1) ldsf[padx(m1 * 16 + lo + 256 * hi)] = v[m1].y;
        __syncthreads();
        #pragma unroll
        for (int a = 0; a < 16; ++a) v[a].y = ldsf[padx(tid + 256 * a)];
        twchain<true>(v, PI2 * (float)tid * (1.0f / 4096.0f));
        fft16<true>(v);
    }
}

// ---------------- weights prep: wtab[d][n] = {A, Bw} (bit-identical to v7's LDS fill) ----
__global__ __launch_bounds__(256) void weights_kernel(
    const float* __restrict__ Bmat, const float* __restrict__ Ct,
    const float2* __restrict__ p, const float2* __restrict__ q,
    const float2* __restrict__ lmbda, float4* __restrict__ wtab)
{
    int idx = blockIdx.x * 256 + threadIdx.x;   // 0..32767
    int d = idx >> 6, n = idx & 63;
    float b  = Bmat[d * 64 + n];
    float ct = Ct[d * 64 + n];
    float2 pp = p[n], qq = q[n];
    float2 lam = lmbda[n];
    wtab[((size_t)d << 7) + 2 * n]     = make_float4(lam.x, lam.y, ct * b, qq.x * pp.x + qq.y * pp.y);
    wtab[((size_t)d << 7) + 2 * n + 1] = make_float4(ct * pp.x, ct * pp.y, b * qq.x, b * qq.y);
}

// ---------------- Cauchy kernel v8: weights from global via wave-uniform (scalar) loads ---
// Same verified math as v7 (conj-halved, real-weight decomposition, honest complex g).
// Weight pointer is blockIdx-uniform -> compiler emits s_load + SGPR-operand FMAs;
// no LDS, no barrier in this kernel.
__global__ __launch_bounds__(256) void cauchy_kernel(
    const float* __restrict__ log_step, const float2* __restrict__ omega,
    const float4* __restrict__ wtab, float2* __restrict__ at)
{
    const int tid = threadIdx.x;
    const int d = blockIdx.x >> 2;
    const int lbase = (blockIdx.x & 3) << 8;   // 0,256,512,768
    const float4* __restrict__ wd = wtab + ((size_t)d << 7);

    const float two_over_dt = 2.0f * __expf(-log_step[d]);
    float2* atd = at + ((size_t)d << 11);

    const int l = lbase + tid;
    float2 om = omega[l];
    float dnx = 1.0f + om.x, dny = om.y;
    float id2 = __builtin_amdgcn_rcpf(dnx * dnx + dny * dny);
    float ivx = dnx * id2, ivy = -dny * id2;       // 1/(1+om)
    float ccx = 2.0f * ivx, ccy = 2.0f * ivy;       // c = 2/(1+om)
    float nmx = 1.0f - om.x, nmy = -om.y;           // 1-om
    float gx = two_over_dt * (nmx * ivx - nmy * ivy); // full complex g
    float gy = two_over_dt * (nmx * ivy + nmy * ivx);

    float S00x = 0.f, S00y = 0.f, Sax = 0.f, Say = 0.f, Sbx = 0.f, Sby = 0.f;
    float Scx = 0.f, Scy = 0.f, Sdx = 0.f, Sdy = 0.f, S11x = 0.f, S11y = 0.f;

    #pragma unroll 8
    for (int n = 0; n < 64; ++n) {
        float4 A  = wd[2 * n];
        float4 Bw = wd[2 * n + 1];
        float dx  = gx - A.x;
        float dy  = gy - A.y;
        float ir  = __builtin_amdgcn_rcpf(fmaf(dx, dx, dy * dy));
        float rx  = dx * ir;
        float ry  = -dy * ir;
        S00x = fmaf(A.z,  rx, S00x); S00y = fmaf(A.z,  ry, S00y);
        S11x = fmaf(A.w,  rx, S11x); S11y = fmaf(A.w,  ry, S11y);
        Sax  = fmaf(Bw.x, rx, Sax);  Say  = fmaf(Bw.x, ry, Say);
        Sbx  = fmaf(Bw.y, rx, Sbx);  Sby  = fmaf(Bw.y, ry, Sby);
        Scx  = fmaf(Bw.z, rx, Scx);  Scy  = fmaf(Bw.z, ry, Scy);
        Sdx  = fmaf(Bw.w, rx, Sdx);  Sdy  = fmaf(Bw.w, ry, Sdy);
    }

    {
        float k01x = Sax - Sby, k01y = Say + Sbx;       // Sa + i*Sb
        float k10x = Scx + Sdy, k10y = Scy - Sdx;       // Sc - i*Sd
        float ntx = k01x * k10x - k01y * k10y;
        float nty = k01x * k10y + k01y * k10x;
        float ox = 1.0f + S11x, oy = S11y;
        float oid = __builtin_amdgcn_rcpf(ox * ox + oy * oy);
        float tx = (ntx * ox + nty * oy) * oid;
        float ty = (nty * ox - ntx * oy) * oid;
        float inx = S00x - tx, iny = S00y - ty;
        float2 val = make_float2(ccx * inx - ccy * iny, ccx * iny + ccy * inx);
        atd[l] = val;
        if (l != 0) atd[2048 - l] = make_float2(val.x, -val.y);   // conj mirror
    }

    // l = 1024 (self-mirror point): one lane per d computes it directly.
    if ((blockIdx.x & 3) == 3 && tid == 0) {
        float2 om1 = omega[1024];
        float dnx1 = 1.0f + om1.x, dny1 = om1.y;
        float id21 = __builtin_amdgcn_rcpf(dnx1 * dnx1 + dny1 * dny1);
        float ivx1 = dnx1 * id21, ivy1 = -dny1 * id21;
        float cx = 2.0f * ivx1, cy = 2.0f * ivy1;
        float nmx1 = 1.0f - om1.x, nmy1 = -om1.y;
        float ggx = two_over_dt * (nmx1 * ivx1 - nmy1 * ivy1);
        float ggy = two_over_dt * (nmx1 * ivy1 + nmy1 * ivx1);
        float s00x = 0.f, s00y = 0.f, sax = 0.f, say = 0.f, sbx = 0.f, sby = 0.f;
        float scx = 0.f, scy = 0.f, sdx = 0.f, sdy = 0.f, s11x = 0.f, s11y = 0.f;
        for (int n = 0; n < 64; ++n) {
            float4 A  = wd[2 * n];
            float4 Bw = wd[2 * n + 1];
            float dx  = ggx - A.x;
            float dy  = ggy - A.y;
            float ir  = __builtin_amdgcn_rcpf(fmaf(dx, dx, dy * dy));
            float rx  = dx * ir;
            float ry  = -dy * ir;
            s00x = fmaf(A.z,  rx, s00x); s00y = fmaf(A.z,  ry, s00y);
            s11x = fmaf(A.w,  rx, s11x); s11y = fmaf(A.w,  ry, s11y);
            sax  = fmaf(Bw.x, rx, sax);  say  = fmaf(Bw.x, ry, say);
            sbx  = fmaf(Bw.y, rx, sbx);  sby  = fmaf(Bw.y, ry, sby);
            scx  = fmaf(Bw.z, rx, scx);  scy  = fmaf(Bw.z, ry, scy);
            sdx  = fmaf(Bw.w, rx, sdx);  sdy  = fmaf(Bw.w, ry, sdy);
        }
        float k01x = sax - sby, k01y = say + sbx;
        float k10x = scx + sdy, k10y = scy - sdx;
        float ntx = k01x * k10x - k01y * k10y;
        float nty = k01x * k10y + k01y * k10x;
        float ox = 1.0f + s11x, oy = s11y;
        float oid = __builtin_amdgcn_rcpf(ox * ox + oy * oy);
        float tx = (ntx * ox + nty * oy) * oid;
        float ty = (nty * ox - ntx * oy) * oid;
        float inx = s00x - tx, iny = s00y - ty;
        atd[1024] = make_float2(cx * inx - cy * iny, cx * iny + cy * inx);
    }
}

// ---------------- khat: 256 threads, one d per block (grid 512), float-LDS FFT ----------
__global__ __launch_bounds__(256) void khat_kernel(
    const float2* __restrict__ at, float2* __restrict__ Khat)
{
    __shared__ float ldsf[LDSN];
    const int tid = threadIdx.x;
    const int d = blockIdx.x;
    const int hi = tid >> 4, lo = tid & 15;
    float2 v[16];

    const float2* ap = at + ((size_t)d << 11);
    #pragma unroll
    for (int n2 = 0; n2 < 8; ++n2) v[n2] = ap[tid + 256 * n2];
    #pragma unroll
    for (int n2 = 8; n2 < 16; ++n2) v[n2] = make_float2(0.f, 0.f);

    fft4096<false>(v, ldsf, tid);

    __syncthreads();
    if (!(hi & 1)) {
        int a2 = hi >> 1;
        #pragma unroll
        for (int c = 0; c < 16; ++c) {
            int j = 128 * c + 8 * lo + a2;
            ldsf[j ^ ((j >> 5) & 3)] = v[c].x * (1.0f / (2048.0f * 4096.0f));
        }
    }
    __syncthreads();
    #pragma unroll
    for (int n2 = 0; n2 < 8; ++n2) {
        int j = tid + 256 * n2;
        v[n2] = make_float2(ldsf[j ^ ((j >> 5) & 3)], 0.f);
    }
    #pragma unroll
    for (int n2 = 8; n2 < 16; ++n2) v[n2] = make_float2(0.f, 0.f);

    fft4096<false>(v, ldsf, tid);

    float2* op = Khat + ((size_t)d << 12);
    #pragma unroll
    for (int c = 0; c < 16; ++c) op[c * 256 + tid] = v[c];
}

// ---------------- transpose: z[bp][d][l] = (u[2bp,l,d], u[2bp+1,l,d]), 64d x 32l tile ------
__global__ __launch_bounds__(256) void transpose_pack_kernel(
    const float* __restrict__ u, float2* __restrict__ z)
{
    __shared__ float2 tile[64][33];
    const int tid = threadIdx.x;
    int sub = blockIdx.x;
    int lt = sub & 63;
    int dt = (sub >> 6) & 7;
    int bp = sub >> 9;
    const size_t ub0 = (size_t)(2 * bp) * 2048 * 512;
    const size_t ub1 = (size_t)(2 * bp + 1) * 2048 * 512;
    #pragma unroll
    for (int r = 0; r < 8; ++r) {
        int idx = tid + 256 * r;
        int l_in = idx >> 6;      // 0..31
        int d_in = idx & 63;      // 0..63
        size_t off = (size_t)(lt * 32 + l_in) * 512 + (dt * 64 + d_in);
        tile[d_in][l_in] = make_float2(u[ub0 + off], u[ub1 + off]);
    }
    __syncthreads();
    #pragma unroll
    for (int r = 0; r < 8; ++r) {
        int idx = tid + 256 * r;
        int d_out = idx >> 5;     // 0..63
        int l_out = idx & 31;     // 0..31
        z[((size_t)(bp * 512 + dt * 64 + d_out)) * 2048 + lt * 32 + l_out] = tile[d_out][l_out];
    }
}

// ---------------- conv: F4096([z,0]) * Khat -> inverse -> y + D*u, in place ----------------
__global__ __launch_bounds__(256) void conv_kernel(
    float2* __restrict__ z, const float2* __restrict__ Khat,
    const float* __restrict__ D)
{
    __shared__ float ldsf[LDSN];
    const int tid = threadIdx.x;
    const int d  = blockIdx.x & 511;
    const int bp = blockIdx.x >> 9;
    float2 v[16];
    float2 u0[8];

    float2* zr = z + ((size_t)(bp * 512 + d)) * 2048;
    #pragma unroll
    for (int n2 = 0; n2 < 8; ++n2) { u0[n2] = zr[tid + 256 * n2]; v[n2] = u0[n2]; }
    #pragma unroll
    for (int n2 = 8; n2 < 16; ++n2) v[n2] = make_float2(0.f, 0.f);

    fft4096<false>(v, ldsf, tid);

    const float2* kh = Khat + ((size_t)d << 12);
    #pragma unroll
    for (int c = 0; c < 16; ++c) v[c] = cmulf(v[c], kh[c * 256 + tid]);

    fft4096<true>(v, ldsf, tid);

    const float Dd = D[d];
    #pragma unroll
    for (int n2 = 0; n2 < 8; ++n2) {
        zr[tid + 256 * n2] =
            make_float2(v[n2].x + Dd * u0[n2].x, v[n2].y + Dd * u0[n2].y);
    }
}

// ---------------- untranspose v2: 64d x 32l tile (16.9 KB -> 8 blocks/CU) ----------------
__global__ __launch_bounds__(256) void untranspose_kernel(
    const float2* __restrict__ yz, float* __restrict__ out)
{
    __shared__ float2 tile[64][33];
    const int tid = threadIdx.x;
    int sub = blockIdx.x;
    int lt = sub & 63;
    int dt = (sub >> 6) & 7;
    int bp = sub >> 9;
    #pragma unroll
    for (int r = 0; r < 8; ++r) {
        int idx = tid + 256 * r;
        int d_in = idx >> 5;      // 0..63
        int l_in = idx & 31;      // 0..31
        tile[d_in][l_in] = yz[((size_t)(bp * 512 + dt * 64 + d_in)) * 2048 + lt * 32 + l_in];
    }
    __syncthreads();
    const size_t ub0 = (size_t)(2 * bp) * 2048 * 512;
    const size_t ub1 = ub0 + (size_t)2048 * 512;
    #pragma unroll
    for (int r = 0; r < 8; ++r) {
        int idx = tid + 256 * r;
        int l_out = idx >> 6;     // 0..31
        int d_out = idx & 63;     // 0..63
        size_t off = (size_t)(lt * 32 + l_out) * 512 + dt * 64 + d_out;
        float2 vv = tile[d_out][l_out];
        out[ub0 + off] = vv.x;
        out[ub1 + off] = vv.y;
    }
}

extern "C" void kernel_launch(void* const* d_in, const int* in_sizes, int n_in,
                              void* d_out, int out_size, void* d_ws, size_t ws_size,
                              hipStream_t stream) {
    (void)in_sizes; (void)n_in; (void)out_size; (void)ws_size;
    const float*  u   = (const float*)d_in[0];
    const float*  Bm  = (const float*)d_in[1];
    const float*  Ct  = (const float*)d_in[2];
    const float*  D   = (const float*)d_in[3];
    const float*  ls  = (const float*)d_in[4];
    const float2* p   = (const float2*)d_in[5];
    const float2* q   = (const float2*)d_in[6];
    const float2* lm  = (const float2*)d_in[7];
    const float2* om  = (const float2*)d_in[8];
    float* out = (float*)d_out;

    const size_t KHAT_B = (size_t)512 * 4096 * sizeof(float2);   // 16.78 MB
    const size_t Z_B    = (size_t)2048 * 2048 * sizeof(float2);  // 33.55 MB

    float2* Khat = (float2*)d_ws;                                // [0, 16.78 MB)
    float2* z    = (float2*)((char*)d_ws + KHAT_B);              // [16.78, 50.33 MB)
    float2* at   = z;   // aliased: consumed by khat before transpose overwrites z
    float4* wtab = (float4*)((char*)d_ws + KHAT_B + Z_B);        // [50.33, 51.38 MB); ws=256MiB

    hipLaunchKernelGGL(weights_kernel, dim3(128), dim3(256), 0, stream,
                       Bm, Ct, p, q, lm, wtab);
    hipLaunchKernelGGL(cauchy_kernel, dim3(2048), dim3(256), 0, stream,
                       ls, om, wtab, at);
    hipLaunchKernelGGL(khat_kernel, dim3(512), dim3(256), 0, stream, at, Khat);
    hipLaunchKernelGGL(transpose_pack_kernel, dim3(2048), dim3(256), 0, stream, u, z);
    hipLaunchKernelGGL(conv_kernel, dim3(2048), dim3(256), 0, stream, z, Khat, D);
    hipLaunchKernelGGL(untranspose_kernel, dim3(2048), dim3(256), 0, stream, z, out);
}

// Round 16
// 86.536 us; speedup vs baseline: 1.0538x; 1.0538x over previous
//
#include <hip/hip_runtime.h>
#include <hip/hip_bf16.h>

#define NT 256
#define R2f 0.70710678118654752f
#define CS1 0.92387953251128674f   // cos(pi/8)
#define SN1 0.38268343236508978f   // sin(pi/8)
#define PI2 6.2831853071795865f
#define LDSN 4336                  // 4096 + 16 pad per 256

__device__ __forceinline__ float2 cmulf(float2 a, float2 b) {
    return make_float2(a.x * b.x - a.y * b.y, a.x * b.y + a.y * b.x);
}
__device__ __forceinline__ float2 cadd(float2 a, float2 b) { return make_float2(a.x + b.x, a.y + b.y); }
__device__ __forceinline__ float2 csub(float2 a, float2 b) { return make_float2(a.x - b.x, a.y - b.y); }
__device__ __forceinline__ int padx(int i) { return i + ((i >> 8) << 4); }   // +16 per 256 segment

template<bool INV>
__device__ __forceinline__ float2 tww(float2 v, float wx, float wy) {
    float sy = INV ? -wy : wy;
    return make_float2(v.x * wx - v.y * sy, v.x * sy + v.y * wx);
}
template<bool INV>
__device__ __forceinline__ float2 mul_mi(float2 v) {
    return INV ? make_float2(-v.y, v.x) : make_float2(v.y, -v.x);
}

template<bool INV>
__device__ __forceinline__ void dft4(float2& a, float2& b, float2& c, float2& d) {
    float2 t0 = cadd(a, c), t1 = csub(a, c);
    float2 t2 = cadd(b, d), t3 = csub(b, d);
    float2 jt3 = mul_mi<INV>(t3);
    a = cadd(t0, t2);
    c = csub(t0, t2);
    b = cadd(t1, jt3);
    d = csub(t1, jt3);
}

template<bool INV>
__device__ __forceinline__ void fft16_tail(float2 v[16]) {
    v[5]  = tww<INV>(v[5],  CS1, -SN1);
    v[9]  = tww<INV>(v[9],  R2f, -R2f);
    v[13] = tww<INV>(v[13], SN1, -CS1);
    v[6]  = tww<INV>(v[6],  R2f, -R2f);
    v[10] = mul_mi<INV>(v[10]);
    v[14] = tww<INV>(v[14], -R2f, -R2f);
    v[7]  = tww<INV>(v[7],  SN1, -CS1);
    v[11] = tww<INV>(v[11], -R2f, -R2f);
    v[15] = tww<INV>(v[15], -CS1,  SN1);
    dft4<INV>(v[0],  v[1],  v[2],  v[3]);
    dft4<INV>(v[4],  v[5],  v[6],  v[7]);
    dft4<INV>(v[8],  v[9],  v[10], v[11]);
    dft4<INV>(v[12], v[13], v[14], v[15]);
    float2 t;
    t = v[1];  v[1]  = v[4];  v[4]  = t;
    t = v[2];  v[2]  = v[8];  v[8]  = t;
    t = v[3];  v[3]  = v[12]; v[12] = t;
    t = v[6];  v[6]  = v[9];  v[9]  = t;
    t = v[7];  v[7]  = v[13]; v[13] = t;
    t = v[11]; v[11] = v[14]; v[14] = t;
}

template<bool INV>
__device__ __forceinline__ void fft16(float2 v[16]) {
    dft4<INV>(v[0], v[4], v[8],  v[12]);
    dft4<INV>(v[1], v[5], v[9],  v[13]);
    dft4<INV>(v[2], v[6], v[10], v[14]);
    dft4<INV>(v[3], v[7], v[11], v[15]);
    fft16_tail<INV>(v);
}

// Forward 16-point DFT with v[8..15] known to be zero on entry.
__device__ __forceinline__ void fft16_hz(float2 v[16]) {
    #pragma unroll
    for (int i = 0; i < 4; ++i) {
        float2 a = v[i], b = v[i + 4];
        float2 jb = make_float2(b.y, -b.x);     // -i*b
        v[i]      = cadd(a, b);
        v[i + 4]  = cadd(a, jb);
        v[i + 8]  = csub(a, b);
        v[i + 12] = csub(a, jb);
    }
    fft16_tail<false>(v);
}

template<bool INV>
__device__ __forceinline__ void twchain(float2 v[16], float ang) {
    float s, c;
    __sincosf(INV ? ang : -ang, &s, &c);
    float2 w = make_float2(c, s);
    float2 t = w;
    v[1] = cmulf(v[1], t);
    #pragma unroll
    for (int a = 2; a < 16; ++a) { t = cmulf(t, w); v[a] = cmulf(v[a], t); }
}

// 4096-pt FFT, 256 threads, 16 regs/thread, float LDS region of LDSN entries.
// Component-split exchanges (x then y) halve LDS vs float2, bit-identical math.
template<bool INV>
__device__ void fft4096(float2 v[16], float* ldsf, int tid) {
    const int hi = tid >> 4, lo = tid & 15;
    if (!INV) {
        fft16_hz(v);
        twchain<false>(v, PI2 * (float)tid * (1.0f / 4096.0f));
        __syncthreads();
        #pragma unroll
        for (int a = 0; a < 16; ++a) ldsf[padx(tid + 256 * a)] = v[a].x;
        __syncthreads();
        #pragma unroll
        for (int m1 = 0; m1 < 16; ++m1) v[m1].x = ldsf[padx(m1 * 16 + lo + 256 * hi)];
        __syncthreads();
        #pragma unroll
        for (int a = 0; a < 16; ++a) ldsf[padx(tid + 256 * a)] = v[a].y;
        __syncthreads();
        #pragma unroll
        for (int m1 = 0; m1 < 16; ++m1) v[m1].y = ldsf[padx(m1 * 16 + lo + 256 * hi)];
        fft16<false>(v);
        twchain<false>(v, PI2 * (float)lo * (1.0f / 256.0f));
        __syncthreads();
        #pragma unroll
        for (int b = 0; b < 16; ++b) ldsf[padx((lo + 16 * b + 256 * hi) ^ b)] = v[b].x;
        __syncthreads();
        #pragma unroll
        for (int m0 = 0; m0 < 16; ++m0) v[m0].x = ldsf[padx((m0 + 16 * lo + 256 * hi) ^ lo)];
        __syncthreads();
        #pragma unroll
        for (int b = 0; b < 16; ++b) ldsf[padx((lo + 16 * b + 256 * hi) ^ b)] = v[b].y;
        __syncthreads();
        #pragma unroll
        for (int m0 = 0; m0 < 16; ++m0) v[m0].y = ldsf[padx((m0 + 16 * lo + 256 * hi) ^ lo)];
        fft16<false>(v);
    } else {
        fft16<true>(v);
        __syncthreads();
        #pragma unroll
        for (int m0 = 0; m0 < 16; ++m0) ldsf[padx((m0 + 16 * lo + 256 * hi) ^ lo)] = v[m0].x;
        __syncthreads();
        #pragma unroll
        for (int b = 0; b < 16; ++b) v[b].x = ldsf[padx((lo + 16 * b + 256 * hi) ^ b)];
        __syncthreads();
        #pragma unroll
        for (int m0 = 0; m0 < 16; ++m0) ldsf[padx((m0 + 16 * lo + 256 * hi) ^ lo)] = v[m0].y;
        __syncthreads();
        #pragma unroll
        for (int b = 0; b < 16; ++b) v[b].y = ldsf[padx((lo + 16 * b + 256 * hi) ^ b)];
        twchain<true>(v, PI2 * (float)lo * (1.0f / 256.0f));
        fft16<true>(v);
        __syncthreads();
        #pragma unroll
        for (int m1 = 0; m1 < 16; ++m1) ldsf[padx(m1 * 16 + lo + 256 * hi)] = v[m1].x;
        __syncthreads();
        #pragma unroll
        for (int a = 0; a < 16; ++a) v[a].x = ldsf[padx(tid + 256 * a)];
        __syncthreads();
        #pragma unroll
        for (int m1 = 0; m1 < 16; ++m1) ldsf[padx(m1 * 16 + lo + 256 * hi)] = v[m1].y;
        __syncthreads();
        #pragma unroll
        for (int a = 0; a < 16; ++a) v[a].y = ldsf[padx(tid + 256 * a)];
        twchain<true>(v, PI2 * (float)tid * (1.0f / 4096.0f));
        fft16<true>(v);
    }
}

// ---------------- Cauchy kernel v7 (verified rounds 12-14; LDS-broadcast weights) --------
__global__ __launch_bounds__(256) void cauchy_kernel(
    const float* __restrict__ Bmat, const float* __restrict__ Ct,
    const float* __restrict__ log_step,
    const float2* __restrict__ p, const float2* __restrict__ q,
    const float2* __restrict__ lmbda, const float2* __restrict__ omega,
    float2* __restrict__ at)
{
    __shared__ float4 wA[64];   // lam.x, lam.y, w00 = Ct*B, w11 = Re(conj(q)*p)
    __shared__ float4 wB[64];   // w01r = Ct*pr, w01i = Ct*pi, w10r = B*qr, w10i = B*qi
    const int tid = threadIdx.x;
    const int d = blockIdx.x >> 2;
    const int lbase = (blockIdx.x & 3) << 8;   // 0,256,512,768

    if (tid < 64) {
        float b  = Bmat[d * 64 + tid];
        float ct = Ct[d * 64 + tid];
        float2 pp = p[tid], qq = q[tid];
        float2 lam = lmbda[tid];
        wA[tid] = make_float4(lam.x, lam.y, ct * b, qq.x * pp.x + qq.y * pp.y);
        wB[tid] = make_float4(ct * pp.x, ct * pp.y, b * qq.x, b * qq.y);
    }
    __syncthreads();

    const float two_over_dt = 2.0f * __expf(-log_step[d]);
    float2* atd = at + ((size_t)d << 11);

    const int l = lbase + tid;
    float2 om = omega[l];
    float dnx = 1.0f + om.x, dny = om.y;
    float id2 = __builtin_amdgcn_rcpf(dnx * dnx + dny * dny);
    float ivx = dnx * id2, ivy = -dny * id2;       // 1/(1+om)
    float ccx = 2.0f * ivx, ccy = 2.0f * ivy;       // c = 2/(1+om)
    float nmx = 1.0f - om.x, nmy = -om.y;           // 1-om
    float gx = two_over_dt * (nmx * ivx - nmy * ivy); // full complex g
    float gy = two_over_dt * (nmx * ivy + nmy * ivx);

    float S00x = 0.f, S00y = 0.f, Sax = 0.f, Say = 0.f, Sbx = 0.f, Sby = 0.f;
    float Scx = 0.f, Scy = 0.f, Sdx = 0.f, Sdy = 0.f, S11x = 0.f, S11y = 0.f;

    #pragma unroll 8
    for (int n = 0; n < 64; ++n) {
        float4 A  = wA[n];
        float4 Bw = wB[n];
        float dx  = gx - A.x;
        float dy  = gy - A.y;
        float ir  = __builtin_amdgcn_rcpf(fmaf(dx, dx, dy * dy));
        float rx  = dx * ir;
        float ry  = -dy * ir;
        S00x = fmaf(A.z,  rx, S00x); S00y = fmaf(A.z,  ry, S00y);
        S11x = fmaf(A.w,  rx, S11x); S11y = fmaf(A.w,  ry, S11y);
        Sax  = fmaf(Bw.x, rx, Sax);  Say  = fmaf(Bw.x, ry, Say);
        Sbx  = fmaf(Bw.y, rx, Sbx);  Sby  = fmaf(Bw.y, ry, Sby);
        Scx  = fmaf(Bw.z, rx, Scx);  Scy  = fmaf(Bw.z, ry, Scy);
        Sdx  = fmaf(Bw.w, rx, Sdx);  Sdy  = fmaf(Bw.w, ry, Sdy);
    }

    {
        float k01x = Sax - Sby, k01y = Say + Sbx;       // Sa + i*Sb
        float k10x = Scx + Sdy, k10y = Scy - Sdx;       // Sc - i*Sd
        float ntx = k01x * k10x - k01y * k10y;
        float nty = k01x * k10y + k01y * k10x;
        float ox = 1.0f + S11x, oy = S11y;
        float oid = __builtin_amdgcn_rcpf(ox * ox + oy * oy);
        float tx = (ntx * ox + nty * oy) * oid;
        float ty = (nty * ox - ntx * oy) * oid;
        float inx = S00x - tx, iny = S00y - ty;
        float2 val = make_float2(ccx * inx - ccy * iny, ccx * iny + ccy * inx);
        atd[l] = val;
        if (l != 0) atd[2048 - l] = make_float2(val.x, -val.y);   // conj mirror
    }

    // l = 1024 (self-mirror point): one lane per d computes it directly.
    if ((blockIdx.x & 3) == 3 && tid == 0) {
        float2 om1 = omega[1024];
        float dnx1 = 1.0f + om1.x, dny1 = om1.y;
        float id21 = __builtin_amdgcn_rcpf(dnx1 * dnx1 + dny1 * dny1);
        float ivx1 = dnx1 * id21, ivy1 = -dny1 * id21;
        float cx = 2.0f * ivx1, cy = 2.0f * ivy1;
        float nmx1 = 1.0f - om1.x, nmy1 = -om1.y;
        float ggx = two_over_dt * (nmx1 * ivx1 - nmy1 * ivy1);
        float ggy = two_over_dt * (nmx1 * ivy1 + nmy1 * ivx1);
        float s00x = 0.f, s00y = 0.f, sax = 0.f, say = 0.f, sbx = 0.f, sby = 0.f;
        float scx = 0.f, scy = 0.f, sdx = 0.f, sdy = 0.f, s11x = 0.f, s11y = 0.f;
        for (int n = 0; n < 64; ++n) {
            float4 A  = wA[n];
            float4 Bw = wB[n];
            float dx  = ggx - A.x;
            float dy  = ggy - A.y;
            float ir  = __builtin_amdgcn_rcpf(fmaf(dx, dx, dy * dy));
            float rx  = dx * ir;
            float ry  = -dy * ir;
            s00x = fmaf(A.z,  rx, s00x); s00y = fmaf(A.z,  ry, s00y);
            s11x = fmaf(A.w,  rx, s11x); s11y = fmaf(A.w,  ry, s11y);
            sax  = fmaf(Bw.x, rx, sax);  say  = fmaf(Bw.x, ry, say);
            sbx  = fmaf(Bw.y, rx, sbx);  sby  = fmaf(Bw.y, ry, sby);
            scx  = fmaf(Bw.z, rx, scx);  scy  = fmaf(Bw.z, ry, scy);
            sdx  = fmaf(Bw.w, rx, sdx);  sdy  = fmaf(Bw.w, ry, sdy);
        }
        float k01x = sax - sby, k01y = say + sbx;
        float k10x = scx + sdy, k10y = scy - sdx;
        float ntx = k01x * k10x - k01y * k10y;
        float nty = k01x * k10y + k01y * k10x;
        float ox = 1.0f + s11x, oy = s11y;
        float oid = __builtin_amdgcn_rcpf(ox * ox + oy * oy);
        float tx = (ntx * ox + nty * oy) * oid;
        float ty = (nty * ox - ntx * oy) * oid;
        float inx = s00x - tx, iny = s00y - ty;
        atd[1024] = make_float2(cx * inx - cy * iny, cx * iny + cy * inx);
    }
}

// ---------------- khat: 256 threads, one d per block (grid 512), float-LDS FFT ----------
__global__ __launch_bounds__(256) void khat_kernel(
    const float2* __restrict__ at, float2* __restrict__ Khat)
{
    __shared__ float ldsf[LDSN];
    const int tid = threadIdx.x;
    const int d = blockIdx.x;
    const int hi = tid >> 4, lo = tid & 15;
    float2 v[16];

    const float2* ap = at + ((size_t)d << 11);
    #pragma unroll
    for (int n2 = 0; n2 < 8; ++n2) v[n2] = ap[tid + 256 * n2];
    #pragma unroll
    for (int n2 = 8; n2 < 16; ++n2) v[n2] = make_float2(0.f, 0.f);

    fft4096<false>(v, ldsf, tid);

    __syncthreads();
    if (!(hi & 1)) {
        int a2 = hi >> 1;
        #pragma unroll
        for (int c = 0; c < 16; ++c) {
            int j = 128 * c + 8 * lo + a2;
            ldsf[j ^ ((j >> 5) & 3)] = v[c].x * (1.0f / (2048.0f * 4096.0f));
        }
    }
    __syncthreads();
    #pragma unroll
    for (int n2 = 0; n2 < 8; ++n2) {
        int j = tid + 256 * n2;
        v[n2] = make_float2(ldsf[j ^ ((j >> 5) & 3)], 0.f);
    }
    #pragma unroll
    for (int n2 = 8; n2 < 16; ++n2) v[n2] = make_float2(0.f, 0.f);

    fft4096<false>(v, ldsf, tid);

    float2* op = Khat + ((size_t)d << 12);
    #pragma unroll
    for (int c = 0; c < 16; ++c) op[c * 256 + tid] = v[c];
}

// ---------------- transpose: z[bp][d][l] = (u[2bp,l,d], u[2bp+1,l,d]), 64d x 32l tile ------
__global__ __launch_bounds__(256) void transpose_pack_kernel(
    const float* __restrict__ u, float2* __restrict__ z)
{
    __shared__ float2 tile[64][33];
    const int tid = threadIdx.x;
    int sub = blockIdx.x;
    int lt = sub & 63;
    int dt = (sub >> 6) & 7;
    int bp = sub >> 9;
    const size_t ub0 = (size_t)(2 * bp) * 2048 * 512;
    const size_t ub1 = (size_t)(2 * bp + 1) * 2048 * 512;
    #pragma unroll
    for (int r = 0; r < 8; ++r) {
        int idx = tid + 256 * r;
        int l_in = idx >> 6;      // 0..31
        int d_in = idx & 63;      // 0..63
        size_t off = (size_t)(lt * 32 + l_in) * 512 + (dt * 64 + d_in);
        tile[d_in][l_in] = make_float2(u[ub0 + off], u[ub1 + off]);
    }
    __syncthreads();
    #pragma unroll
    for (int r = 0; r < 8; ++r) {
        int idx = tid + 256 * r;
        int d_out = idx >> 5;     // 0..63
        int l_out = idx & 31;     // 0..31
        z[((size_t)(bp * 512 + dt * 64 + d_out)) * 2048 + lt * 32 + l_out] = tile[d_out][l_out];
    }
}

// ---------------- conv: F4096([z,0]) * Khat -> inverse -> y + D*u, in place ----------------
__global__ __launch_bounds__(256) void conv_kernel(
    float2* __restrict__ z, const float2* __restrict__ Khat,
    const float* __restrict__ D)
{
    __shared__ float ldsf[LDSN];
    const int tid = threadIdx.x;
    const int d  = blockIdx.x & 511;
    const int bp = blockIdx.x >> 9;
    float2 v[16];
    float2 u0[8];

    float2* zr = z + ((size_t)(bp * 512 + d)) * 2048;
    #pragma unroll
    for (int n2 = 0; n2 < 8; ++n2) { u0[n2] = zr[tid + 256 * n2]; v[n2] = u0[n2]; }
    #pragma unroll
    for (int n2 = 8; n2 < 16; ++n2) v[n2] = make_float2(0.f, 0.f);

    fft4096<false>(v, ldsf, tid);

    const float2* kh = Khat + ((size_t)d << 12);
    #pragma unroll
    for (int c = 0; c < 16; ++c) v[c] = cmulf(v[c], kh[c * 256 + tid]);

    fft4096<true>(v, ldsf, tid);

    const float Dd = D[d];
    #pragma unroll
    for (int n2 = 0; n2 < 8; ++n2) {
        zr[tid + 256 * n2] =
            make_float2(v[n2].x + Dd * u0[n2].x, v[n2].y + Dd * u0[n2].y);
    }
}

// ---------------- untranspose v2: 64d x 32l tile (16.9 KB -> 8 blocks/CU) ----------------
__global__ __launch_bounds__(256) void untranspose_kernel(
    const float2* __restrict__ yz, float* __restrict__ out)
{
    __shared__ float2 tile[64][33];
    const int tid = threadIdx.x;
    int sub = blockIdx.x;
    int lt = sub & 63;
    int dt = (sub >> 6) & 7;
    int bp = sub >> 9;
    #pragma unroll
    for (int r = 0; r < 8; ++r) {
        int idx = tid + 256 * r;
        int d_in = idx >> 5;      // 0..63
        int l_in = idx & 31;      // 0..31
        tile[d_in][l_in] = yz[((size_t)(bp * 512 + dt * 64 + d_in)) * 2048 + lt * 32 + l_in];
    }
    __syncthreads();
    const size_t ub0 = (size_t)(2 * bp) * 2048 * 512;
    const size_t ub1 = ub0 + (size_t)2048 * 512;
    #pragma unroll
    for (int r = 0; r < 8; ++r) {
        int idx = tid + 256 * r;
        int l_out = idx >> 6;     // 0..31
        int d_out = idx & 63;     // 0..63
        size_t off = (size_t)(lt * 32 + l_out) * 512 + dt * 64 + d_out;
        float2 vv = tile[d_out][l_out];
        out[ub0 + off] = vv.x;
        out[ub1 + off] = vv.y;
    }
}

extern "C" void kernel_launch(void* const* d_in, const int* in_sizes, int n_in,
                              void* d_out, int out_size, void* d_ws, size_t ws_size,
                              hipStream_t stream) {
    (void)in_sizes; (void)n_in; (void)out_size; (void)ws_size;
    const float*  u   = (const float*)d_in[0];
    const float*  Bm  = (const float*)d_in[1];
    const float*  Ct  = (const float*)d_in[2];
    const float*  D   = (const float*)d_in[3];
    const float*  ls  = (const float*)d_in[4];
    const float2* p   = (const float2*)d_in[5];
    const float2* q   = (const float2*)d_in[6];
    const float2* lm  = (const float2*)d_in[7];
    const float2* om  = (const float2*)d_in[8];
    float* out = (float*)d_out;

    float2* Khat = (float2*)d_ws;                                    // 16.78 MB
    float2* z    = (float2*)((char*)d_ws + (size_t)512 * 4096 * 8);  // 33.55 MB
    float2* at   = z;  // aliased: consumed by khat_kernel before transpose overwrites z

    hipLaunchKernelGGL(cauchy_kernel, dim3(2048), dim3(256), 0, stream,
                       Bm, Ct, ls, p, q, lm, om, at);
    hipLaunchKernelGGL(khat_kernel, dim3(512), dim3(256), 0, stream, at, Khat);
    hipLaunchKernelGGL(transpose_pack_kernel, dim3(2048), dim3(256), 0, stream, u, z);
    hipLaunchKernelGGL(conv_kernel, dim3(2048), dim3(256), 0, stream, z, Khat, D);
    hipLaunchKernelGGL(untranspose_kernel, dim3(2048), dim3(256), 0, stream, z, out);
}